// Round 18
// baseline (150.311 us; speedup 1.0000x reference)
//
#include <hip/hip_runtime.h>

typedef __attribute__((ext_vector_type(16))) float f32x16;
typedef __attribute__((ext_vector_type(2))) long lv2;
typedef __attribute__((ext_vector_type(2))) unsigned int uint2v;

#define BN_EPS 1e-5f
#define KOFF 27
#define LSTRIDE 72   // act LDS row stride in bytes (64B row + 8B pad)

static __device__ __forceinline__ float silu_f(float z) {
  return z / (1.f + __expf(-z));
}

// f32 -> fp8 e4m3 (OCP on gfx950), RNE+sat via HW cvt
static __device__ __forceinline__ unsigned char f2fp8(float v) {
  unsigned int p = (unsigned int)__builtin_amdgcn_cvt_pk_fp8_f32(v, 0.f, 0, 0);
  return (unsigned char)(p & 0xffu);
}

// ---- fused prep:
// [0,54)          : pack W1+W2 via LDS-tiled transpose (coalesced reads).
// [54,62)         : time MLP (f32)
// [62,62+vblk)    : vmask[n] = bitmask of valid[k][n], k=0..26
// [62+vblk, ...)  : a1 = fp8(silu(bn1(x))), 8 elems/thread; zero row N
__global__ void prep_all(int vblk,
                         const float* __restrict__ t, const float* __restrict__ Wt,
                         const float* __restrict__ bt,
                         float* __restrict__ scale_eff, float* __restrict__ shift,
                         const float* __restrict__ W1, const float* __restrict__ W2,
                         unsigned char* __restrict__ Wp1, unsigned char* __restrict__ Wp2,
                         const int* __restrict__ kval, unsigned int* __restrict__ vmask,
                         const float* __restrict__ x, const float* __restrict__ g1,
                         const float* __restrict__ b1, const float* __restrict__ m1,
                         const float* __restrict__ v1, unsigned char* __restrict__ a1,
                         int N, int total) {
  __shared__ float tile[4096];
  const int bid = blockIdx.x;
  const int tid = threadIdx.x;
  if (bid < 54) {
    int which = bid >= KOFF;
    int k = bid - which * KOFF;
    const float* Wk = (which ? W2 : W1) + (size_t)k * 4096;
    unsigned char* Wp = (which ? Wp2 : Wp1) + (size_t)k * 4096;
#pragma unroll
    for (int j = 0; j < 16; ++j) tile[j * 256 + tid] = Wk[j * 256 + tid];
    __syncthreads();
    int f = tid >> 5;
    int lane0 = (tid & 31) * 2;
    alignas(16) unsigned char obuf[16];
#pragma unroll
    for (int li = 0; li < 2; ++li) {
      int lane = lane0 + li;
      int cib = (f >> 1) * 16 + (lane >> 5) * 8;
      int co = (f & 1) * 32 + (lane & 31);
#pragma unroll
      for (int j = 0; j < 8; ++j)
        obuf[li * 8 + j] = f2fp8(tile[(cib + j) * 64 + co]);
    }
    *(lv2*)(Wp + tid * 16) = *(const lv2*)obuf;
  } else if (bid < 62) {
    int id = (bid - 54) * 256 + tid;  // 0..2047 = 16 batches * 128 out
    int bi = id >> 7, co = id & 127;
    float acc = bt[co];
    for (int e = 0; e < 256; ++e) {
      float tv = t[bi * 256 + e];
      acc += silu_f(tv) * Wt[e * 128 + co];
    }
    if (co < 64) scale_eff[bi * 64 + co] = 1.f + acc;
    else         shift[bi * 64 + (co - 64)] = acc;
  } else if (bid < 62 + vblk) {
    int n = (bid - 62) * 256 + tid;
    if (n < N) {
      unsigned int u = 0;
#pragma unroll
      for (int k = 0; k < KOFF; ++k)
        u |= (kval[(size_t)k * N + n] ? 1u : 0u) << k;
      vmask[n] = u;
    }
  } else {
    int i = ((bid - 62 - vblk) * 256 + tid) * 8;
    if (i >= total) {
      if (i < total + 64) *(uint2v*)(a1 + i) = (uint2v){0u, 0u};   // zero row N
      return;
    }
    float4 va = *(const float4*)(x + i);
    float4 vb = *(const float4*)(x + i + 4);
    int c = i & 63;
    float4 ga = *(const float4*)(g1 + c), gb = *(const float4*)(g1 + c + 4);
    float4 ba = *(const float4*)(b1 + c), bbv = *(const float4*)(b1 + c + 4);
    float4 ma = *(const float4*)(m1 + c), mb = *(const float4*)(m1 + c + 4);
    float4 vva = *(const float4*)(v1 + c), vvb = *(const float4*)(v1 + c + 4);
    float z0 = silu_f((va.x - ma.x) * (ga.x * rsqrtf(vva.x + BN_EPS)) + ba.x);
    float z1 = silu_f((va.y - ma.y) * (ga.y * rsqrtf(vva.y + BN_EPS)) + ba.y);
    float z2 = silu_f((va.z - ma.z) * (ga.z * rsqrtf(vva.z + BN_EPS)) + ba.z);
    float z3 = silu_f((va.w - ma.w) * (ga.w * rsqrtf(vva.w + BN_EPS)) + ba.w);
    float z4 = silu_f((vb.x - mb.x) * (gb.x * rsqrtf(vvb.x + BN_EPS)) + bbv.x);
    float z5 = silu_f((vb.y - mb.y) * (gb.y * rsqrtf(vvb.y + BN_EPS)) + bbv.y);
    float z6 = silu_f((vb.z - mb.z) * (gb.z * rsqrtf(vvb.z + BN_EPS)) + bbv.z);
    float z7 = silu_f((vb.w - mb.w) * (gb.w * rsqrtf(vvb.w + BN_EPS)) + bbv.w);
    unsigned int w0 = (unsigned int)__builtin_amdgcn_cvt_pk_fp8_f32(z0, z1, 0, 0);
    w0 = (unsigned int)__builtin_amdgcn_cvt_pk_fp8_f32(z2, z3, (int)w0, 1);
    unsigned int w1 = (unsigned int)__builtin_amdgcn_cvt_pk_fp8_f32(z4, z5, 0, 0);
    w1 = (unsigned int)__builtin_amdgcn_cvt_pk_fp8_f32(z6, z7, (int)w1, 1);
    *(uint2v*)(a1 + i) = (uint2v){w0, w1};
  }
}

// ---- sparse conv, fp8: 256-thread blocks, DEPTH-5 act gather + DEPTH-3 W prefetch.
// Wave w: rows (w>>1)*32..+31, cols (w&1)*32..+31. Act: thread covers row
// rL = wid*16 + (lane>>2), chunk q0=lane&3. W via LDS ring (4KB/tap, tid*16).
// Index: vm = vmask[nS] once; GRPLOAD(g): idx[4g+q0][nS] (1 instr per 4 taps);
//   rI[g&1][q0][rL]; GRPLOAD at k%4==0 (k<=16), RINGWRITE at k%4==2 (k<=18);
//   RINGREAD(t) = bit(vm,t) ? rI[(t>>2)&1][t&3][rL] : N. Only reader is GLOAD(k+5);
//   group (k+5)>>2 is written by iter k (verified k=0..26); 2 slots suffice.
// Pipeline at iter k (rotation hand-traced k=0..26, consume-before-refill holds):
//   DSWRITE(k+1)<-st[(k+1)%5] (gathered at k-4) ; DSWRITE_W(k+1)<-wst[(k+1)%3] (k-2);
//   GRP/RING per k%4 ; WGLOAD(k+3)->wst[k%3] ; GLOAD(k+5)->st[k%5] (row from ring);
//   COMPUTE(k) on buf k&1 ; s_waitcnt lgkmcnt(0); s_barrier  (vmcnt NOT drained)
// Act gather now has ~5 iterations of latency cover (vs 3 in R16).
// MODE 0: epilogue FiLM+bn2+silu -> fp8 a2 (block 0 zeroes a2 row N)
// MODE 1: epilogue +bias+residual -> f32 out
template <int MODE>
__global__ __launch_bounds__(256, 8) void conv_k(
    const unsigned char* __restrict__ act, const int* __restrict__ idx,
    const unsigned int* __restrict__ vmask,
    const unsigned char* __restrict__ Wp,
    const float* __restrict__ bias,
    const float* __restrict__ scale_eff, const float* __restrict__ shift,
    const int* __restrict__ bidx,
    const float* __restrict__ g2, const float* __restrict__ b2,
    const float* __restrict__ m2, const float* __restrict__ v2,
    const float* __restrict__ xres,
    unsigned char* __restrict__ out8, float* __restrict__ out_f, int N) {
  __shared__ unsigned char ldsA[2][64 * LSTRIDE];
  __shared__ unsigned char ldsW[2][4096];
  __shared__ int rI[2][4][64];

  if (MODE == 0 && blockIdx.x == 0 && threadIdx.x < 64) {
    out8[(size_t)N * 64 + threadIdx.x] = 0;  // zero row for conv2's invalid taps
  }
  const int tid = threadIdx.x;
  const int lane = tid & 63;
  const int wid = tid >> 6;
  const int half = lane >> 5;   // 0/1
  const int r32 = lane & 31;
  const int n0 = blockIdx.x * 64;

  const int q0 = lane & 3;                // 16B chunk within the 64B act row
  const int rL = wid * 16 + (lane >> 2);  // act row this thread stages
  const int nS = min(n0 + rL, N - 1);     // node for that row
  const int RH = wid >> 1;
  const int cb = wid & 1;

  f32x16 acc;
#pragma unroll
  for (int i = 0; i < 16; ++i) acc[i] = 0.f;

  lv2 st0, st1, st2, st3, st4;   // staged act chunks, slot = tap%5
  lv2 wst0, wst1, wst2;          // staged W chunks, slot = tap%3
  int gr = 0;                    // grouped-index staging register
  const unsigned int vm = vmask[nS];

#define GRPLOAD(g) do { \
    int tp = min(4 * (g) + q0, KOFF - 1); \
    gr = idx[(size_t)tp * N + nS]; \
  } while (0)

#define RINGWRITE(g) do { rI[(g) & 1][q0][rL] = gr; } while (0)

#define RINGREAD(t) \
    (((vm >> (t)) & 1u) ? rI[((t) >> 2) & 1][(t) & 3][rL] : N)

#define GLOAD(st, rv) do { \
    st = *(const lv2*)(act + (size_t)(rv) * 64 + q0 * 16); \
  } while (0)

#define WGLOAD(kk, wst) do { \
    wst = *(const lv2*)(Wp + (size_t)(kk) * 4096 + tid * 16); \
  } while (0)

#define DSWRITE(buf, st) do { \
    unsigned char* _p = &ldsA[buf][rL * LSTRIDE + q0 * 16]; \
    *(long*)_p = st.x; \
    *(long*)(_p + 8) = st.y; \
  } while (0)

#define DSWRITE_W(buf, wst) do { \
    unsigned char* _p = &ldsW[buf][tid * 16]; \
    *(long*)_p = wst.x; \
    *(long*)(_p + 8) = wst.y; \
  } while (0)

#define COMPUTE(buf) do { \
    _Pragma("unroll") \
    for (int ks = 0; ks < 4; ++ks) { \
      long av = *(const long*)(&ldsA[buf][(RH * 32 + r32) * LSTRIDE + ks * 16 + half * 8]); \
      long wv = *(const long*)(&ldsW[buf][((ks * 2 + cb) * 64 + lane) * 8]); \
      acc = __builtin_amdgcn_mfma_f32_32x32x16_fp8_fp8(av, wv, acc, 0, 0, 0); \
    } } while (0)

#define BARRIER() do { \
    asm volatile("s_waitcnt lgkmcnt(0)" ::: "memory"); \
    __builtin_amdgcn_s_barrier(); \
  } while (0)

  // prologue: idx groups 0,1 (taps 0..7) -> ring; gather taps 0..4; W taps 0..2
  GRPLOAD(0); RINGWRITE(0);
  GRPLOAD(1); RINGWRITE(1);
  BARRIER();                 // ring visible
  {
    int rv;
    rv = RINGREAD(0); GLOAD(st0, rv);
    rv = RINGREAD(1); GLOAD(st1, rv);
    rv = RINGREAD(2); GLOAD(st2, rv);
    rv = RINGREAD(3); GLOAD(st3, rv);
    rv = RINGREAD(4); GLOAD(st4, rv);
  }
  WGLOAD(0, wst0);
  WGLOAD(1, wst1);
  WGLOAD(2, wst2);
  DSWRITE(0, st0);           // compiler inserts counted vmcnt for st0/wst0 here
  DSWRITE_W(0, wst0);
  BARRIER();

#pragma unroll
  for (int k = 0; k < KOFF; ++k) {
    if (k + 1 < KOFF) {          // stage tap k+1 into LDS slot (k+1)&1
      const int s5 = (k + 1) % 5;
      if (s5 == 0)      DSWRITE((k + 1) & 1, st0);
      else if (s5 == 1) DSWRITE((k + 1) & 1, st1);
      else if (s5 == 2) DSWRITE((k + 1) & 1, st2);
      else if (s5 == 3) DSWRITE((k + 1) & 1, st3);
      else              DSWRITE((k + 1) & 1, st4);
      const int s3 = (k + 1) % 3;
      if (s3 == 0)      DSWRITE_W((k + 1) & 1, wst0);
      else if (s3 == 1) DSWRITE_W((k + 1) & 1, wst1);
      else              DSWRITE_W((k + 1) & 1, wst2);
    }
    if (!(k & 3) && k <= 16)      GRPLOAD(k / 4 + 2);    // taps 4g..4g+3 -> reg
    if ((k & 3) == 2 && k <= 18)  RINGWRITE(k / 4 + 2);  // reg -> ring
    if (k + 3 < KOFF) {          // W tap k+3 -> wst[k%3]
      const int s3 = k % 3;
      if (s3 == 0)      WGLOAD(k + 3, wst0);
      else if (s3 == 1) WGLOAD(k + 3, wst1);
      else              WGLOAD(k + 3, wst2);
    }
    if (k + 5 < KOFF) {          // act tap k+5 -> st[k%5], row from ring
      int rv = RINGREAD(k + 5);
      const int s5 = k % 5;
      if (s5 == 0)      GLOAD(st0, rv);
      else if (s5 == 1) GLOAD(st1, rv);
      else if (s5 == 2) GLOAD(st2, rv);
      else if (s5 == 3) GLOAD(st3, rv);
      else              GLOAD(st4, rv);
    }
    COMPUTE(k & 1);
    if (k + 1 < KOFF) BARRIER();
  }
#undef GRPLOAD
#undef RINGWRITE
#undef RINGREAD
#undef GLOAD
#undef WGLOAD
#undef DSWRITE
#undef DSWRITE_W
#undef COMPUTE
#undef BARRIER

  // D frag: col = cb*32 + r32, row = RH*32 + (r&3) + 8*(r>>2) + 4*half (dtype-independent)
  if (MODE == 0) {
    const int c = cb * 32 + r32;
    float bb = bias[c];
    float s2v = g2[c] * rsqrtf(v2[c] + BN_EPS);
    float o2v = b2[c] - m2[c] * s2v;
#pragma unroll
    for (int r = 0; r < 16; ++r) {
      int rowD = (r & 3) + 8 * (r >> 2) + 4 * half;
      int n = n0 + RH * 32 + rowD;
      if (n < N) {
        int bi = bidx[n];
        float h = acc[r] + bb;
        h = scale_eff[bi * 64 + c] * h + shift[bi * 64 + c];
        float z = h * s2v + o2v;
        out8[(size_t)n * 64 + c] = f2fp8(silu_f(z));
      }
    }
  } else {
    const int c = cb * 32 + r32;
    float bb = bias[c];
#pragma unroll
    for (int r = 0; r < 16; ++r) {
      int rowD = (r & 3) + 8 * (r >> 2) + 4 * half;
      int n = n0 + RH * 32 + rowD;
      if (n < N) {
        out_f[(size_t)n * 64 + c] = acc[r] + bb + xres[(size_t)n * 64 + c];
      }
    }
  }
}

extern "C" void kernel_launch(void* const* d_in, const int* in_sizes, int n_in,
                              void* d_out, int out_size, void* d_ws, size_t ws_size,
                              hipStream_t stream) {
  const float* x    = (const float*)d_in[0];
  const float* t    = (const float*)d_in[1];
  const int*   b    = (const int*)d_in[2];
  const int*   kidx = (const int*)d_in[3];
  const int*   kval = (const int*)d_in[4];
  const float* bn1g = (const float*)d_in[5];
  const float* bn1b = (const float*)d_in[6];
  const float* bn1m = (const float*)d_in[7];
  const float* bn1v = (const float*)d_in[8];
  const float* W1   = (const float*)d_in[9];
  const float* b1c  = (const float*)d_in[10];
  const float* bn2g = (const float*)d_in[11];
  const float* bn2b = (const float*)d_in[12];
  const float* bn2m = (const float*)d_in[13];
  const float* bn2v = (const float*)d_in[14];
  const float* W2   = (const float*)d_in[15];
  const float* b2c  = (const float*)d_in[16];
  const float* Wt   = (const float*)d_in[17];
  const float* bt   = (const float*)d_in[18];
  float* out = (float*)d_out;

  const int N = in_sizes[2];        // 100000
  const int total = N * 64;

  // workspace layout (bytes); act buffers have N+1 rows (row N = zeros), fp8
  char* ws = (char*)d_ws;
  size_t actB = ((size_t)(N + 1) * 64 + 255) & ~(size_t)255;       // 6.4 MB
  unsigned char* a1 = (unsigned char*)ws;
  unsigned char* a2 = (unsigned char*)(ws + actB);
  const size_t wpackB = (size_t)KOFF * 8 * 64 * 8;                 // 110592 B
  unsigned char* W1p = (unsigned char*)(ws + 2 * actB);
  unsigned char* W2p = (unsigned char*)(ws + 2 * actB + wpackB);
  float* scale_eff = (float*)(ws + 2 * actB + 2 * wpackB);
  float* shiftp    = scale_eff + 16 * 64;
  unsigned int* vmask = (unsigned int*)(ws + 2 * actB + 2 * wpackB + 8192);

  int vblk = (N + 255) / 256;
  int bnblk = (total / 8 + 8 + 255) / 256;
  prep_all<<<62 + vblk + bnblk, 256, 0, stream>>>(vblk, t, Wt, bt, scale_eff, shiftp,
                                                  W1, W2, W1p, W2p, kval, vmask,
                                                  x, bn1g, bn1b, bn1m, bn1v, a1,
                                                  N, total);

  int nblk = (N + 63) / 64;
  conv_k<0><<<nblk, 256, 0, stream>>>(a1, kidx, vmask, W1p, b1c, scale_eff,
                                      shiftp, b, bn2g, bn2b, bn2m, bn2v,
                                      nullptr, a2, nullptr, N);
  conv_k<1><<<nblk, 256, 0, stream>>>(a2, kidx, vmask, W2p, b2c, nullptr, nullptr,
                                      nullptr, nullptr, nullptr, nullptr, nullptr,
                                      x, nullptr, out, N);
}

// Round 19
// 104.742 us; speedup vs baseline: 1.4351x; 1.4351x over previous
//
#include <hip/hip_runtime.h>

typedef __attribute__((ext_vector_type(16))) float f32x16;
typedef __attribute__((ext_vector_type(2))) long lv2;
typedef __attribute__((ext_vector_type(2))) unsigned int uint2v;

#define BN_EPS 1e-5f
#define KOFF 27
#define LSTRIDE 72   // act LDS row stride in bytes (64B row + 8B pad)

static __device__ __forceinline__ float silu_f(float z) {
  return z / (1.f + __expf(-z));
}

// f32 -> fp8 e4m3 (OCP on gfx950), RNE+sat via HW cvt
static __device__ __forceinline__ unsigned char f2fp8(float v) {
  unsigned int p = (unsigned int)__builtin_amdgcn_cvt_pk_fp8_f32(v, 0.f, 0, 0);
  return (unsigned char)(p & 0xffu);
}

// ---- fused prep:
// [0,54)          : pack W1+W2 via LDS-tiled transpose (coalesced reads).
//                   block = (which,k); frag f: lane l byte j <-
//                   W[k][(f>>1)*16+(l>>5)*8+j][(f&1)*32+(l&31)]
// [54,62)         : time MLP (f32)
// [62,62+vblk)    : vmask[n] = bitmask of valid[k][n], k=0..26
// [62+vblk, ...)  : a1 = fp8(silu(bn1(x))), 8 elems/thread; zero row N
__global__ void prep_all(int vblk,
                         const float* __restrict__ t, const float* __restrict__ Wt,
                         const float* __restrict__ bt,
                         float* __restrict__ scale_eff, float* __restrict__ shift,
                         const float* __restrict__ W1, const float* __restrict__ W2,
                         unsigned char* __restrict__ Wp1, unsigned char* __restrict__ Wp2,
                         const int* __restrict__ kval, unsigned int* __restrict__ vmask,
                         const float* __restrict__ x, const float* __restrict__ g1,
                         const float* __restrict__ b1, const float* __restrict__ m1,
                         const float* __restrict__ v1, unsigned char* __restrict__ a1,
                         int N, int total) {
  __shared__ float tile[4096];
  const int bid = blockIdx.x;
  const int tid = threadIdx.x;
  if (bid < 54) {
    int which = bid >= KOFF;
    int k = bid - which * KOFF;
    const float* Wk = (which ? W2 : W1) + (size_t)k * 4096;
    unsigned char* Wp = (which ? Wp2 : Wp1) + (size_t)k * 4096;
#pragma unroll
    for (int j = 0; j < 16; ++j) tile[j * 256 + tid] = Wk[j * 256 + tid];
    __syncthreads();
    // thread t emits bytes [t*16, t*16+16): f = t>>5, lanes (t&31)*2, +1
    int f = tid >> 5;
    int lane0 = (tid & 31) * 2;
    alignas(16) unsigned char obuf[16];
#pragma unroll
    for (int li = 0; li < 2; ++li) {
      int lane = lane0 + li;
      int cib = (f >> 1) * 16 + (lane >> 5) * 8;
      int co = (f & 1) * 32 + (lane & 31);
#pragma unroll
      for (int j = 0; j < 8; ++j)
        obuf[li * 8 + j] = f2fp8(tile[(cib + j) * 64 + co]);
    }
    *(lv2*)(Wp + tid * 16) = *(const lv2*)obuf;
  } else if (bid < 62) {
    int id = (bid - 54) * 256 + tid;  // 0..2047 = 16 batches * 128 out
    int bi = id >> 7, co = id & 127;
    float acc = bt[co];
    for (int e = 0; e < 256; ++e) {
      float tv = t[bi * 256 + e];
      acc += silu_f(tv) * Wt[e * 128 + co];
    }
    if (co < 64) scale_eff[bi * 64 + co] = 1.f + acc;
    else         shift[bi * 64 + (co - 64)] = acc;
  } else if (bid < 62 + vblk) {
    int n = (bid - 62) * 256 + tid;
    if (n < N) {
      unsigned int u = 0;
#pragma unroll
      for (int k = 0; k < KOFF; ++k)
        u |= (kval[(size_t)k * N + n] ? 1u : 0u) << k;
      vmask[n] = u;
    }
  } else {
    int i = ((bid - 62 - vblk) * 256 + tid) * 8;
    if (i >= total) {
      if (i < total + 64) *(uint2v*)(a1 + i) = (uint2v){0u, 0u};   // zero row N
      return;
    }
    float4 va = *(const float4*)(x + i);
    float4 vb = *(const float4*)(x + i + 4);
    int c = i & 63;
    float4 ga = *(const float4*)(g1 + c), gb = *(const float4*)(g1 + c + 4);
    float4 ba = *(const float4*)(b1 + c), bbv = *(const float4*)(b1 + c + 4);
    float4 ma = *(const float4*)(m1 + c), mb = *(const float4*)(m1 + c + 4);
    float4 vva = *(const float4*)(v1 + c), vvb = *(const float4*)(v1 + c + 4);
    float z0 = silu_f((va.x - ma.x) * (ga.x * rsqrtf(vva.x + BN_EPS)) + ba.x);
    float z1 = silu_f((va.y - ma.y) * (ga.y * rsqrtf(vva.y + BN_EPS)) + ba.y);
    float z2 = silu_f((va.z - ma.z) * (ga.z * rsqrtf(vva.z + BN_EPS)) + ba.z);
    float z3 = silu_f((va.w - ma.w) * (ga.w * rsqrtf(vva.w + BN_EPS)) + ba.w);
    float z4 = silu_f((vb.x - mb.x) * (gb.x * rsqrtf(vvb.x + BN_EPS)) + bbv.x);
    float z5 = silu_f((vb.y - mb.y) * (gb.y * rsqrtf(vvb.y + BN_EPS)) + bbv.y);
    float z6 = silu_f((vb.z - mb.z) * (gb.z * rsqrtf(vvb.z + BN_EPS)) + bbv.z);
    float z7 = silu_f((vb.w - mb.w) * (gb.w * rsqrtf(vvb.w + BN_EPS)) + bbv.w);
    unsigned int w0 = (unsigned int)__builtin_amdgcn_cvt_pk_fp8_f32(z0, z1, 0, 0);
    w0 = (unsigned int)__builtin_amdgcn_cvt_pk_fp8_f32(z2, z3, (int)w0, 1);
    unsigned int w1 = (unsigned int)__builtin_amdgcn_cvt_pk_fp8_f32(z4, z5, 0, 0);
    w1 = (unsigned int)__builtin_amdgcn_cvt_pk_fp8_f32(z6, z7, (int)w1, 1);
    *(uint2v*)(a1 + i) = (uint2v){w0, w1};
  }
}

// ---- sparse conv, fp8, W via LDS + 4-tap grouped idx ring + vmask bitmask.
// (R16-verified structure: depth-3 act, depth-2 W — the measured optimum of the
// gather-latency / L2-capacity equilibrium. R19 adds non-temporal hints on
// streaming traffic (idx, xres, out) to preserve L2 capacity for act gathers.)
// Block = 256 threads / 4 waves / 64 nodes. Wave w: rows (w>>1)*32..+31, cols (w&1)*32..+31.
// Act staging: thread covers row rL = wid*16 + (lane>>2), chunk q0=lane&3 (16B).
// Validity: vm = vmask[nS] loaded ONCE (bit t = tap-t valid for this row).
// Index loads: ONE nt instr/wave per 4 taps (q0 picks tap): GRPLOAD(g) loads
//   idx[4g+q0][nS] -> reg; RINGWRITE -> rI[g&1][q0][rL].
//   GRPLOAD at k%4==0 (k<=16); RINGWRITE at k%4==2 (k<=18);
//   RINGREAD(t) = bit(vm,t) ? rI[(t>>2)&1][t&3][rL] : N (rotation R16-verified).
// Steady-state VMEM/wave/tap: GLOAD 1 + WGLOAD 1 + idx 0.25 = 2.25.
// Pipeline at iter k:
//   DSWRITE(k+1)<-st[(k+1)%3] ; DSWRITE_W(k+1)<-wst[(k+1)&1] ; GRP/RING per k%4 ;
//   WGLOAD(k+2)->wst[k&1] ; GLOAD(k+3)<-ring ; COMPUTE(k) ;
//   s_waitcnt lgkmcnt(0); s_barrier   (vmcnt NOT drained)
// MODE 0: epilogue FiLM+bn2+silu -> fp8 a2 (block 0 zeroes a2 row N)
// MODE 1: epilogue +bias+residual (nt read xres, nt write out)
template <int MODE>
__global__ __launch_bounds__(256, 8) void conv_k(
    const unsigned char* __restrict__ act, const int* __restrict__ idx,
    const unsigned int* __restrict__ vmask,
    const unsigned char* __restrict__ Wp,
    const float* __restrict__ bias,
    const float* __restrict__ scale_eff, const float* __restrict__ shift,
    const int* __restrict__ bidx,
    const float* __restrict__ g2, const float* __restrict__ b2,
    const float* __restrict__ m2, const float* __restrict__ v2,
    const float* __restrict__ xres,
    unsigned char* __restrict__ out8, float* __restrict__ out_f, int N) {
  __shared__ unsigned char ldsA[2][64 * LSTRIDE];
  __shared__ unsigned char ldsW[2][4096];
  __shared__ int rI[2][4][64];

  if (MODE == 0 && blockIdx.x == 0 && threadIdx.x < 64) {
    out8[(size_t)N * 64 + threadIdx.x] = 0;  // zero row for conv2's invalid taps
  }
  const int tid = threadIdx.x;
  const int lane = tid & 63;
  const int wid = tid >> 6;
  const int half = lane >> 5;   // 0/1
  const int r32 = lane & 31;
  const int n0 = blockIdx.x * 64;

  const int q0 = lane & 3;                // 16B chunk within the 64B act row
  const int rL = wid * 16 + (lane >> 2);  // act row this thread stages
  const int nS = min(n0 + rL, N - 1);     // node for that row
  const int RH = wid >> 1;
  const int cb = wid & 1;

  f32x16 acc;
#pragma unroll
  for (int i = 0; i < 16; ++i) acc[i] = 0.f;

  lv2 st0, st1, st2;       // staged act chunks, slot = tap%3
  lv2 wstA, wstB;          // staged W chunk (16B/thread), slot = tap&1
  int gr = 0;              // grouped-index staging register
  const unsigned int vm = vmask[nS];

#define GRPLOAD(g) do { \
    int tp = min(4 * (g) + q0, KOFF - 1); \
    gr = __builtin_nontemporal_load(idx + (size_t)tp * N + nS); \
  } while (0)

#define RINGWRITE(g) do { rI[(g) & 1][q0][rL] = gr; } while (0)

#define RINGREAD(t) \
    (((vm >> (t)) & 1u) ? rI[((t) >> 2) & 1][(t) & 3][rL] : N)

#define GLOAD(st, rv) do { \
    st = *(const lv2*)(act + (size_t)(rv) * 64 + q0 * 16); \
  } while (0)

#define WGLOAD(kk, wst) do { \
    wst = *(const lv2*)(Wp + (size_t)(kk) * 4096 + tid * 16); \
  } while (0)

#define DSWRITE(buf, st) do { \
    unsigned char* _p = &ldsA[buf][rL * LSTRIDE + q0 * 16]; \
    *(long*)_p = st.x; \
    *(long*)(_p + 8) = st.y; \
  } while (0)

#define DSWRITE_W(buf, wst) do { \
    unsigned char* _p = &ldsW[buf][tid * 16]; \
    *(long*)_p = wst.x; \
    *(long*)(_p + 8) = wst.y; \
  } while (0)

#define COMPUTE(buf) do { \
    _Pragma("unroll") \
    for (int ks = 0; ks < 4; ++ks) { \
      long av = *(const long*)(&ldsA[buf][(RH * 32 + r32) * LSTRIDE + ks * 16 + half * 8]); \
      long wv = *(const long*)(&ldsW[buf][((ks * 2 + cb) * 64 + lane) * 8]); \
      acc = __builtin_amdgcn_mfma_f32_32x32x16_fp8_fp8(av, wv, acc, 0, 0, 0); \
    } } while (0)

#define BARRIER() do { \
    asm volatile("s_waitcnt lgkmcnt(0)" ::: "memory"); \
    __builtin_amdgcn_s_barrier(); \
  } while (0)

  // prologue: idx groups 0,1 (taps 0..7) -> ring; gather taps 0..2; W 0,1
  GRPLOAD(0); RINGWRITE(0);
  GRPLOAD(1); RINGWRITE(1);
  BARRIER();                 // ring visible
  {
    int rv0 = RINGREAD(0);
    GLOAD(st0, rv0);
    int rv1 = RINGREAD(1);
    GLOAD(st1, rv1);
    int rv2 = RINGREAD(2);
    GLOAD(st2, rv2);
  }
  WGLOAD(0, wstA);
  WGLOAD(1, wstB);
  DSWRITE(0, st0);           // compiler inserts counted vmcnt for st0/wstA here
  DSWRITE_W(0, wstA);
  BARRIER();

#pragma unroll
  for (int k = 0; k < KOFF; ++k) {
    if (k + 1 < KOFF) {          // stage tap k+1 into LDS slot (k+1)&1
      const int s = (k + 1) % 3;
      if (s == 0)      DSWRITE((k + 1) & 1, st0);
      else if (s == 1) DSWRITE((k + 1) & 1, st1);
      else             DSWRITE((k + 1) & 1, st2);
      if ((k + 1) & 1) DSWRITE_W(1, wstB); else DSWRITE_W(0, wstA);
    }
    if (!(k & 3) && k <= 16)      GRPLOAD(k / 4 + 2);    // taps 4g..4g+3 -> reg
    if ((k & 3) == 2 && k <= 18)  RINGWRITE(k / 4 + 2);  // reg -> ring
    if (k + 2 < KOFF) {          // W tap k+2 -> wst[k&1]
      if (k & 1) WGLOAD(k + 2, wstB); else WGLOAD(k + 2, wstA);
    }
    if (k + 3 < KOFF) {          // act tap k+3 -> st[(k+3)%3], row from ring
      int rv = RINGREAD(k + 3);
      const int s = (k + 3) % 3;
      if (s == 0)      GLOAD(st0, rv);
      else if (s == 1) GLOAD(st1, rv);
      else             GLOAD(st2, rv);
    }
    COMPUTE(k & 1);
    if (k + 1 < KOFF) BARRIER();
  }
#undef GRPLOAD
#undef RINGWRITE
#undef RINGREAD
#undef GLOAD
#undef WGLOAD
#undef DSWRITE
#undef DSWRITE_W
#undef COMPUTE
#undef BARRIER

  // D frag: col = cb*32 + r32, row = RH*32 + (r&3) + 8*(r>>2) + 4*half (dtype-independent)
  if (MODE == 0) {
    const int c = cb * 32 + r32;
    float bb = bias[c];
    float s2v = g2[c] * rsqrtf(v2[c] + BN_EPS);
    float o2v = b2[c] - m2[c] * s2v;
#pragma unroll
    for (int r = 0; r < 16; ++r) {
      int rowD = (r & 3) + 8 * (r >> 2) + 4 * half;
      int n = n0 + RH * 32 + rowD;
      if (n < N) {
        int bi = bidx[n];
        float h = acc[r] + bb;
        h = scale_eff[bi * 64 + c] * h + shift[bi * 64 + c];
        float z = h * s2v + o2v;
        out8[(size_t)n * 64 + c] = f2fp8(silu_f(z));
      }
    }
  } else {
    const int c = cb * 32 + r32;
    float bb = bias[c];
#pragma unroll
    for (int r = 0; r < 16; ++r) {
      int rowD = (r & 3) + 8 * (r >> 2) + 4 * half;
      int n = n0 + RH * 32 + rowD;
      if (n < N) {
        float xr = __builtin_nontemporal_load(xres + (size_t)n * 64 + c);
        __builtin_nontemporal_store(acc[r] + bb + xr, out_f + (size_t)n * 64 + c);
      }
    }
  }
}

extern "C" void kernel_launch(void* const* d_in, const int* in_sizes, int n_in,
                              void* d_out, int out_size, void* d_ws, size_t ws_size,
                              hipStream_t stream) {
  const float* x    = (const float*)d_in[0];
  const float* t    = (const float*)d_in[1];
  const int*   b    = (const int*)d_in[2];
  const int*   kidx = (const int*)d_in[3];
  const int*   kval = (const int*)d_in[4];
  const float* bn1g = (const float*)d_in[5];
  const float* bn1b = (const float*)d_in[6];
  const float* bn1m = (const float*)d_in[7];
  const float* bn1v = (const float*)d_in[8];
  const float* W1   = (const float*)d_in[9];
  const float* b1c  = (const float*)d_in[10];
  const float* bn2g = (const float*)d_in[11];
  const float* bn2b = (const float*)d_in[12];
  const float* bn2m = (const float*)d_in[13];
  const float* bn2v = (const float*)d_in[14];
  const float* W2   = (const float*)d_in[15];
  const float* b2c  = (const float*)d_in[16];
  const float* Wt   = (const float*)d_in[17];
  const float* bt   = (const float*)d_in[18];
  float* out = (float*)d_out;

  const int N = in_sizes[2];        // 100000
  const int total = N * 64;

  // workspace layout (bytes); act buffers have N+1 rows (row N = zeros), fp8
  char* ws = (char*)d_ws;
  size_t actB = ((size_t)(N + 1) * 64 + 255) & ~(size_t)255;       // 6.4 MB
  unsigned char* a1 = (unsigned char*)ws;
  unsigned char* a2 = (unsigned char*)(ws + actB);
  const size_t wpackB = (size_t)KOFF * 8 * 64 * 8;                 // 110592 B
  unsigned char* W1p = (unsigned char*)(ws + 2 * actB);
  unsigned char* W2p = (unsigned char*)(ws + 2 * actB + wpackB);
  float* scale_eff = (float*)(ws + 2 * actB + 2 * wpackB);
  float* shiftp    = scale_eff + 16 * 64;
  unsigned int* vmask = (unsigned int*)(ws + 2 * actB + 2 * wpackB + 8192);

  int vblk = (N + 255) / 256;
  int bnblk = (total / 8 + 8 + 255) / 256;
  prep_all<<<62 + vblk + bnblk, 256, 0, stream>>>(vblk, t, Wt, bt, scale_eff, shiftp,
                                                  W1, W2, W1p, W2p, kval, vmask,
                                                  x, bn1g, bn1b, bn1m, bn1v, a1,
                                                  N, total);

  int nblk = (N + 63) / 64;
  conv_k<0><<<nblk, 256, 0, stream>>>(a1, kidx, vmask, W1p, b1c, scale_eff,
                                      shiftp, b, bn2g, bn2b, bn2m, bn2v,
                                      nullptr, a2, nullptr, N);
  conv_k<1><<<nblk, 256, 0, stream>>>(a2, kidx, vmask, W2p, b2c, nullptr, nullptr,
                                      nullptr, nullptr, nullptr, nullptr, nullptr,
                                      x, nullptr, out, N);
}

// Round 20
// 100.784 us; speedup vs baseline: 1.4914x; 1.0393x over previous
//
#include <hip/hip_runtime.h>

typedef __attribute__((ext_vector_type(16))) float f32x16;
typedef __attribute__((ext_vector_type(2))) long lv2;
typedef __attribute__((ext_vector_type(2))) unsigned int uint2v;

#define BN_EPS 1e-5f
#define KOFF 27
#define LSTRIDE 72   // act LDS row stride in bytes (64B row + 8B pad)

static __device__ __forceinline__ float silu_f(float z) {
  return z / (1.f + __expf(-z));
}

// f32 -> fp8 e4m3 (OCP on gfx950), RNE+sat via HW cvt
static __device__ __forceinline__ unsigned char f2fp8(float v) {
  unsigned int p = (unsigned int)__builtin_amdgcn_cvt_pk_fp8_f32(v, 0.f, 0, 0);
  return (unsigned char)(p & 0xffu);
}

// ---- fused prep:
// [0,54)          : pack W1+W2 via LDS-tiled transpose (coalesced reads).
//                   block = (which,k); frag f: lane l byte j <-
//                   W[k][(f>>1)*16+(l>>5)*8+j][(f&1)*32+(l&31)]
// [54,62)         : time MLP (f32)
// [62,62+vblk)    : vmask[n] = bitmask of valid[k][n], k=0..26
// [62+vblk, ...)  : a1 = fp8(silu(bn1(x))), 8 elems/thread; zero row N
__global__ void prep_all(int vblk,
                         const float* __restrict__ t, const float* __restrict__ Wt,
                         const float* __restrict__ bt,
                         float* __restrict__ scale_eff, float* __restrict__ shift,
                         const float* __restrict__ W1, const float* __restrict__ W2,
                         unsigned char* __restrict__ Wp1, unsigned char* __restrict__ Wp2,
                         const int* __restrict__ kval, unsigned int* __restrict__ vmask,
                         const float* __restrict__ x, const float* __restrict__ g1,
                         const float* __restrict__ b1, const float* __restrict__ m1,
                         const float* __restrict__ v1, unsigned char* __restrict__ a1,
                         int N, int total) {
  __shared__ float tile[4096];
  const int bid = blockIdx.x;
  const int tid = threadIdx.x;
  if (bid < 54) {
    int which = bid >= KOFF;
    int k = bid - which * KOFF;
    const float* Wk = (which ? W2 : W1) + (size_t)k * 4096;
    unsigned char* Wp = (which ? Wp2 : Wp1) + (size_t)k * 4096;
#pragma unroll
    for (int j = 0; j < 16; ++j) tile[j * 256 + tid] = Wk[j * 256 + tid];
    __syncthreads();
    // thread t emits bytes [t*16, t*16+16): f = t>>5, lanes (t&31)*2, +1
    int f = tid >> 5;
    int lane0 = (tid & 31) * 2;
    alignas(16) unsigned char obuf[16];
#pragma unroll
    for (int li = 0; li < 2; ++li) {
      int lane = lane0 + li;
      int cib = (f >> 1) * 16 + (lane >> 5) * 8;
      int co = (f & 1) * 32 + (lane & 31);
#pragma unroll
      for (int j = 0; j < 8; ++j)
        obuf[li * 8 + j] = f2fp8(tile[(cib + j) * 64 + co]);
    }
    *(lv2*)(Wp + tid * 16) = *(const lv2*)obuf;
  } else if (bid < 62) {
    int id = (bid - 54) * 256 + tid;  // 0..2047 = 16 batches * 128 out
    int bi = id >> 7, co = id & 127;
    float acc = bt[co];
    for (int e = 0; e < 256; ++e) {
      float tv = t[bi * 256 + e];
      acc += silu_f(tv) * Wt[e * 128 + co];
    }
    if (co < 64) scale_eff[bi * 64 + co] = 1.f + acc;
    else         shift[bi * 64 + (co - 64)] = acc;
  } else if (bid < 62 + vblk) {
    int n = (bid - 62) * 256 + tid;
    if (n < N) {
      unsigned int u = 0;
#pragma unroll
      for (int k = 0; k < KOFF; ++k)
        u |= (kval[(size_t)k * N + n] ? 1u : 0u) << k;
      vmask[n] = u;
    }
  } else {
    int i = ((bid - 62 - vblk) * 256 + tid) * 8;
    if (i >= total) {
      if (i < total + 64) *(uint2v*)(a1 + i) = (uint2v){0u, 0u};   // zero row N
      return;
    }
    float4 va = *(const float4*)(x + i);
    float4 vb = *(const float4*)(x + i + 4);
    int c = i & 63;
    float4 ga = *(const float4*)(g1 + c), gb = *(const float4*)(g1 + c + 4);
    float4 ba = *(const float4*)(b1 + c), bbv = *(const float4*)(b1 + c + 4);
    float4 ma = *(const float4*)(m1 + c), mb = *(const float4*)(m1 + c + 4);
    float4 vva = *(const float4*)(v1 + c), vvb = *(const float4*)(v1 + c + 4);
    float z0 = silu_f((va.x - ma.x) * (ga.x * rsqrtf(vva.x + BN_EPS)) + ba.x);
    float z1 = silu_f((va.y - ma.y) * (ga.y * rsqrtf(vva.y + BN_EPS)) + ba.y);
    float z2 = silu_f((va.z - ma.z) * (ga.z * rsqrtf(vva.z + BN_EPS)) + ba.z);
    float z3 = silu_f((va.w - ma.w) * (ga.w * rsqrtf(vva.w + BN_EPS)) + ba.w);
    float z4 = silu_f((vb.x - mb.x) * (gb.x * rsqrtf(vvb.x + BN_EPS)) + bbv.x);
    float z5 = silu_f((vb.y - mb.y) * (gb.y * rsqrtf(vvb.y + BN_EPS)) + bbv.y);
    float z6 = silu_f((vb.z - mb.z) * (gb.z * rsqrtf(vvb.z + BN_EPS)) + bbv.z);
    float z7 = silu_f((vb.w - mb.w) * (gb.w * rsqrtf(vvb.w + BN_EPS)) + bbv.w);
    unsigned int w0 = (unsigned int)__builtin_amdgcn_cvt_pk_fp8_f32(z0, z1, 0, 0);
    w0 = (unsigned int)__builtin_amdgcn_cvt_pk_fp8_f32(z2, z3, (int)w0, 1);
    unsigned int w1 = (unsigned int)__builtin_amdgcn_cvt_pk_fp8_f32(z4, z5, 0, 0);
    w1 = (unsigned int)__builtin_amdgcn_cvt_pk_fp8_f32(z6, z7, (int)w1, 1);
    *(uint2v*)(a1 + i) = (uint2v){w0, w1};
  }
}

// ---- sparse conv, fp8, W via LDS + 4-tap grouped idx ring + vmask bitmask.
// (R16 configuration — the measured optimum of the gather-latency / L2-capacity
// equilibrium: depth-3 act pipeline, depth-2 W, cached idx loads.)
// Block = 256 threads / 4 waves / 64 nodes. Wave w: rows (w>>1)*32..+31, cols (w&1)*32..+31.
// Act staging: thread covers row rL = wid*16 + (lane>>2), chunk q0=lane&3 (16B).
// Validity: vm = vmask[nS] loaded ONCE (bit t = tap-t valid for this row).
// Index loads: ONE instr/wave per 4 taps (q0 picks tap): GRPLOAD(g) loads
//   idx[4g+q0][nS] -> reg; RINGWRITE -> rI[g&1][q0][rL].
//   GRPLOAD at k%4==0 (k<=16), RINGWRITE at k%4==2 (k<=18);
//   RINGREAD(t) = bit(vm,t) ? rI[(t>>2)&1][t&3][rL] : N (rotation R16-verified).
// Steady-state VMEM/wave/tap: GLOAD 1 + WGLOAD 1 + idx 0.25 = 2.25.
// Pipeline at iter k:
//   DSWRITE(k+1)<-st[(k+1)%3] ; DSWRITE_W(k+1)<-wst[(k+1)&1] ; GRP/RING per k%4 ;
//   WGLOAD(k+2)->wst[k&1] ; GLOAD(k+3)<-ring ; COMPUTE(k) ;
//   s_waitcnt lgkmcnt(0); s_barrier   (vmcnt NOT drained)
// MODE 0: epilogue FiLM+bn2+silu -> fp8 a2 (block 0 zeroes a2 row N)
// MODE 1: epilogue +bias+residual -> f32 out
template <int MODE>
__global__ __launch_bounds__(256, 8) void conv_k(
    const unsigned char* __restrict__ act, const int* __restrict__ idx,
    const unsigned int* __restrict__ vmask,
    const unsigned char* __restrict__ Wp,
    const float* __restrict__ bias,
    const float* __restrict__ scale_eff, const float* __restrict__ shift,
    const int* __restrict__ bidx,
    const float* __restrict__ g2, const float* __restrict__ b2,
    const float* __restrict__ m2, const float* __restrict__ v2,
    const float* __restrict__ xres,
    unsigned char* __restrict__ out8, float* __restrict__ out_f, int N) {
  __shared__ unsigned char ldsA[2][64 * LSTRIDE];
  __shared__ unsigned char ldsW[2][4096];
  __shared__ int rI[2][4][64];

  if (MODE == 0 && blockIdx.x == 0 && threadIdx.x < 64) {
    out8[(size_t)N * 64 + threadIdx.x] = 0;  // zero row for conv2's invalid taps
  }
  const int tid = threadIdx.x;
  const int lane = tid & 63;
  const int wid = tid >> 6;
  const int half = lane >> 5;   // 0/1
  const int r32 = lane & 31;
  const int n0 = blockIdx.x * 64;

  const int q0 = lane & 3;                // 16B chunk within the 64B act row
  const int rL = wid * 16 + (lane >> 2);  // act row this thread stages
  const int nS = min(n0 + rL, N - 1);     // node for that row
  const int RH = wid >> 1;
  const int cb = wid & 1;

  f32x16 acc;
#pragma unroll
  for (int i = 0; i < 16; ++i) acc[i] = 0.f;

  lv2 st0, st1, st2;       // staged act chunks, slot = tap%3
  lv2 wstA, wstB;          // staged W chunk (16B/thread), slot = tap&1
  int gr = 0;              // grouped-index staging register
  const unsigned int vm = vmask[nS];

#define GRPLOAD(g) do { \
    int tp = min(4 * (g) + q0, KOFF - 1); \
    gr = idx[(size_t)tp * N + nS]; \
  } while (0)

#define RINGWRITE(g) do { rI[(g) & 1][q0][rL] = gr; } while (0)

#define RINGREAD(t) \
    (((vm >> (t)) & 1u) ? rI[((t) >> 2) & 1][(t) & 3][rL] : N)

#define GLOAD(st, rv) do { \
    st = *(const lv2*)(act + (size_t)(rv) * 64 + q0 * 16); \
  } while (0)

#define WGLOAD(kk, wst) do { \
    wst = *(const lv2*)(Wp + (size_t)(kk) * 4096 + tid * 16); \
  } while (0)

#define DSWRITE(buf, st) do { \
    unsigned char* _p = &ldsA[buf][rL * LSTRIDE + q0 * 16]; \
    *(long*)_p = st.x; \
    *(long*)(_p + 8) = st.y; \
  } while (0)

#define DSWRITE_W(buf, wst) do { \
    unsigned char* _p = &ldsW[buf][tid * 16]; \
    *(long*)_p = wst.x; \
    *(long*)(_p + 8) = wst.y; \
  } while (0)

#define COMPUTE(buf) do { \
    _Pragma("unroll") \
    for (int ks = 0; ks < 4; ++ks) { \
      long av = *(const long*)(&ldsA[buf][(RH * 32 + r32) * LSTRIDE + ks * 16 + half * 8]); \
      long wv = *(const long*)(&ldsW[buf][((ks * 2 + cb) * 64 + lane) * 8]); \
      acc = __builtin_amdgcn_mfma_f32_32x32x16_fp8_fp8(av, wv, acc, 0, 0, 0); \
    } } while (0)

#define BARRIER() do { \
    asm volatile("s_waitcnt lgkmcnt(0)" ::: "memory"); \
    __builtin_amdgcn_s_barrier(); \
  } while (0)

  // prologue: idx groups 0,1 (taps 0..7) -> ring; gather taps 0..2; W 0,1
  GRPLOAD(0); RINGWRITE(0);
  GRPLOAD(1); RINGWRITE(1);
  BARRIER();                 // ring visible
  {
    int rv0 = RINGREAD(0);
    GLOAD(st0, rv0);
    int rv1 = RINGREAD(1);
    GLOAD(st1, rv1);
    int rv2 = RINGREAD(2);
    GLOAD(st2, rv2);
  }
  WGLOAD(0, wstA);
  WGLOAD(1, wstB);
  DSWRITE(0, st0);           // compiler inserts counted vmcnt for st0/wstA here
  DSWRITE_W(0, wstA);
  BARRIER();

#pragma unroll
  for (int k = 0; k < KOFF; ++k) {
    if (k + 1 < KOFF) {          // stage tap k+1 into LDS slot (k+1)&1
      const int s = (k + 1) % 3;
      if (s == 0)      DSWRITE((k + 1) & 1, st0);
      else if (s == 1) DSWRITE((k + 1) & 1, st1);
      else             DSWRITE((k + 1) & 1, st2);
      if ((k + 1) & 1) DSWRITE_W(1, wstB); else DSWRITE_W(0, wstA);
    }
    if (!(k & 3) && k <= 16)      GRPLOAD(k / 4 + 2);    // taps 4g..4g+3 -> reg
    if ((k & 3) == 2 && k <= 18)  RINGWRITE(k / 4 + 2);  // reg -> ring
    if (k + 2 < KOFF) {          // W tap k+2 -> wst[k&1]
      if (k & 1) WGLOAD(k + 2, wstB); else WGLOAD(k + 2, wstA);
    }
    if (k + 3 < KOFF) {          // act tap k+3 -> st[(k+3)%3], row from ring
      int rv = RINGREAD(k + 3);
      const int s = (k + 3) % 3;
      if (s == 0)      GLOAD(st0, rv);
      else if (s == 1) GLOAD(st1, rv);
      else             GLOAD(st2, rv);
    }
    COMPUTE(k & 1);
    if (k + 1 < KOFF) BARRIER();
  }
#undef GRPLOAD
#undef RINGWRITE
#undef RINGREAD
#undef GLOAD
#undef WGLOAD
#undef DSWRITE
#undef DSWRITE_W
#undef COMPUTE
#undef BARRIER

  // D frag: col = cb*32 + r32, row = RH*32 + (r&3) + 8*(r>>2) + 4*half (dtype-independent)
  if (MODE == 0) {
    const int c = cb * 32 + r32;
    float bb = bias[c];
    float s2v = g2[c] * rsqrtf(v2[c] + BN_EPS);
    float o2v = b2[c] - m2[c] * s2v;
#pragma unroll
    for (int r = 0; r < 16; ++r) {
      int rowD = (r & 3) + 8 * (r >> 2) + 4 * half;
      int n = n0 + RH * 32 + rowD;
      if (n < N) {
        int bi = bidx[n];
        float h = acc[r] + bb;
        h = scale_eff[bi * 64 + c] * h + shift[bi * 64 + c];
        float z = h * s2v + o2v;
        out8[(size_t)n * 64 + c] = f2fp8(silu_f(z));
      }
    }
  } else {
    const int c = cb * 32 + r32;
    float bb = bias[c];
#pragma unroll
    for (int r = 0; r < 16; ++r) {
      int rowD = (r & 3) + 8 * (r >> 2) + 4 * half;
      int n = n0 + RH * 32 + rowD;
      if (n < N) {
        out_f[(size_t)n * 64 + c] = acc[r] + bb + xres[(size_t)n * 64 + c];
      }
    }
  }
}

extern "C" void kernel_launch(void* const* d_in, const int* in_sizes, int n_in,
                              void* d_out, int out_size, void* d_ws, size_t ws_size,
                              hipStream_t stream) {
  const float* x    = (const float*)d_in[0];
  const float* t    = (const float*)d_in[1];
  const int*   b    = (const int*)d_in[2];
  const int*   kidx = (const int*)d_in[3];
  const int*   kval = (const int*)d_in[4];
  const float* bn1g = (const float*)d_in[5];
  const float* bn1b = (const float*)d_in[6];
  const float* bn1m = (const float*)d_in[7];
  const float* bn1v = (const float*)d_in[8];
  const float* W1   = (const float*)d_in[9];
  const float* b1c  = (const float*)d_in[10];
  const float* bn2g = (const float*)d_in[11];
  const float* bn2b = (const float*)d_in[12];
  const float* bn2m = (const float*)d_in[13];
  const float* bn2v = (const float*)d_in[14];
  const float* W2   = (const float*)d_in[15];
  const float* b2c  = (const float*)d_in[16];
  const float* Wt   = (const float*)d_in[17];
  const float* bt   = (const float*)d_in[18];
  float* out = (float*)d_out;

  const int N = in_sizes[2];        // 100000
  const int total = N * 64;

  // workspace layout (bytes); act buffers have N+1 rows (row N = zeros), fp8
  char* ws = (char*)d_ws;
  size_t actB = ((size_t)(N + 1) * 64 + 255) & ~(size_t)255;       // 6.4 MB
  unsigned char* a1 = (unsigned char*)ws;
  unsigned char* a2 = (unsigned char*)(ws + actB);
  const size_t wpackB = (size_t)KOFF * 8 * 64 * 8;                 // 110592 B
  unsigned char* W1p = (unsigned char*)(ws + 2 * actB);
  unsigned char* W2p = (unsigned char*)(ws + 2 * actB + wpackB);
  float* scale_eff = (float*)(ws + 2 * actB + 2 * wpackB);
  float* shiftp    = scale_eff + 16 * 64;
  unsigned int* vmask = (unsigned int*)(ws + 2 * actB + 2 * wpackB + 8192);

  int vblk = (N + 255) / 256;
  int bnblk = (total / 8 + 8 + 255) / 256;
  prep_all<<<62 + vblk + bnblk, 256, 0, stream>>>(vblk, t, Wt, bt, scale_eff, shiftp,
                                                  W1, W2, W1p, W2p, kval, vmask,
                                                  x, bn1g, bn1b, bn1m, bn1v, a1,
                                                  N, total);

  int nblk = (N + 63) / 64;
  conv_k<0><<<nblk, 256, 0, stream>>>(a1, kidx, vmask, W1p, b1c, scale_eff,
                                      shiftp, b, bn2g, bn2b, bn2m, bn2v,
                                      nullptr, a2, nullptr, N);
  conv_k<1><<<nblk, 256, 0, stream>>>(a2, kidx, vmask, W2p, b2c, nullptr, nullptr,
                                      nullptr, nullptr, nullptr, nullptr, nullptr,
                                      x, nullptr, out, N);
}